// Round 4
// baseline (355.171 us; speedup 1.0000x reference)
//
#include <hip/hip_runtime.h>

// Problem: B=8, C=256, H=W=64, K=3, pad=1, stride=1
// out_flat[bc*36864 + p] = kflat_bc[p] * qc_bc[p/9]
// where p = j*4096 + l, j=kh*3+kw, l=h*64+w, kflat value = plane[h+kh-1,w+kw-1],
// and qc[l2] = qflat[l2*9+4] (center-tap query factor).
//
// V4b: same as V4 (compile fix: __builtin_nontemporal_store needs a native
// clang vector type, not HIP_vector_type float4).
// Theory recap: V1(353.4)==V3(351.9) despite very different inner-loop ALU ->
// kernel is not ALU/chain-bound; shared structure was 32 KB LDS -> 5 blocks/CU
// (20/32 waves) and 2048 blocks / 1280 resident = 1.6 passes (60%-idle tail).
// Now: LDS holds ONLY the 16 KB qc table (irregular gathers; q-from-global
// proven bad in V2); regular coalesced k reads come from global and hit L1/L2
// after the first tap pass (per-XCD k footprint 512 KB << 4 MB L2). 16 KB LDS
// + launch_bounds(256,8) -> 8 blocks/CU = 32 waves, one full resident pass,
// no tail. Nontemporal output stores keep the 302 MB write stream from
// evicting k-planes from L2.
#define HW 4096

typedef float vfloat4 __attribute__((ext_vector_type(4)));

__global__ __launch_bounds__(256, 8) void appcomp_kernel(
    const float* __restrict__ key,
    const float* __restrict__ query,
    float* __restrict__ out)
{
    __shared__ float q_s[HW];   // staged q plane, then overwritten with qc table

    const int bc  = blockIdx.x;          // 2048 blocks, one per (b,c)
    const int tid = threadIdx.x;
    const float* __restrict__ kp = key + bc * HW;

    // Phase 1: stage q plane, fully coalesced float4.
    {
        const float4* qg = (const float4*)(query + bc * HW);
        float4* q4 = (float4*)q_s;
        #pragma unroll
        for (int i = 0; i < 4; i++) {
            int idx = i * 256 + tid;
            q4[idx] = qg[idx];
        }
    }
    __syncthreads();

    // Phase 1b: decode each center value exactly once -> registers.
    // stride-9 LDS addresses -> conflict-free (gcd(9,32)=1).
    float qc[16];
    #pragma unroll
    for (int s = 0; s < 16; s++) {
        int l2  = s * 256 + tid;
        int idx = l2 * 9 + 4;
        int j4  = idx >> 12;
        int l4  = idx & 4095;
        int h4  = l4 >> 6;
        int w4  = l4 & 63;
        int jd  = (j4 * 11) >> 5;          // j4/3 for j4 in [0,8]
        int hh  = h4 + jd - 1;
        int ww  = w4 + (j4 - jd * 3) - 1;
        qc[s] = ((unsigned)hh < 64u && (unsigned)ww < 64u)
                    ? q_s[(hh << 6) + ww] : 0.0f;
    }
    __syncthreads();   // all reads of the raw q plane done

    // Phase 1c: overwrite q_s with the qc table (stride-1, conflict-free).
    #pragma unroll
    for (int s = 0; s < 16; s++)
        q_s[s * 256 + tid] = qc[s];
    __syncthreads();

    // Phase 2: 36 chunks of 4 consecutive outputs per thread.
    // k comes straight from global (L1/L2-resident after first tap pass).
    float* oplane = out + (size_t)bc * 36864;
    #pragma unroll 2
    for (int i = 0; i < 36; i++) {
        int t  = i * 256 + tid;          // chunk id in [0, 9216)
        int r  = t << 2;                 // base p, [0, 36864)
        int j  = t >> 10;                // tap index 0..8 (wave-uniform)
        int l  = r & 4095;
        int h  = l >> 6;
        int w0 = l & 63;                 // multiple of 4

        int jd3 = (j * 11) >> 5;         // j/3
        int dh  = jd3 - 1;
        int dw  = j - jd3 * 3 - 1;       // wave-uniform
        int hh  = h + dh;

        float kf[4];
        if ((unsigned)hh < 64u) {
            const float* rowp = kp + (hh << 6);
            float4 a = *(const float4*)(rowp + w0);      // coalesced global
            if (dw == 0) {
                kf[0] = a.x; kf[1] = a.y; kf[2] = a.z; kf[3] = a.w;
            } else if (dw < 0) {
                kf[0] = (w0 > 0) ? rowp[w0 - 1] : 0.0f;
                kf[1] = a.x; kf[2] = a.y; kf[3] = a.z;
            } else {
                kf[0] = a.y; kf[1] = a.z; kf[2] = a.w;
                kf[3] = (w0 < 60) ? rowp[w0 + 4] : 0.0f;
            }
        } else {
            kf[0] = kf[1] = kf[2] = kf[3] = 0.0f;
        }

        // query factors: 4 consecutive p span at most two l2 = p/9 values.
        int l2a   = r / 9;
        int m9    = r - l2a * 9;
        int split = 9 - m9;              // [0, split) use qa, rest qb
        int l2b   = l2a + 1;
        if (l2b > 4095) l2b = 4095;      // qb unused when l2a==4095
        float qa = q_s[l2a];
        float qb = q_s[l2b];

        vfloat4 f;
        f.x = kf[0] * ((0 < split) ? qa : qb);
        f.y = kf[1] * ((1 < split) ? qa : qb);
        f.z = kf[2] * ((2 < split) ? qa : qb);
        f.w = kf[3] * ((3 < split) ? qa : qb);

        __builtin_nontemporal_store(f, (vfloat4*)(oplane + r));
    }
}

extern "C" void kernel_launch(void* const* d_in, const int* in_sizes, int n_in,
                              void* d_out, int out_size, void* d_ws, size_t ws_size,
                              hipStream_t stream) {
    const float* key   = (const float*)d_in[0];
    const float* query = (const float*)d_in[1];
    float* out = (float*)d_out;
    appcomp_kernel<<<2048, 256, 0, stream>>>(key, query, out);
}